// Round 9
// baseline (478.837 us; speedup 1.0000x reference)
//
#include <hip/hip_runtime.h>
#include <hip/hip_bf16.h>

#define N_NODES 50000
#define N_EDGES 800000
// HEADS=4, OUT_CH=64, F=256 hard-coded. All harness I/O float32.
// Internal H layout PLAIN head-major: H[node*256 + head*64 + c] (bf16)

typedef __attribute__((ext_vector_type(8))) short short8;   // 8 bf16 = 4 VGPRs (MFMA A/B frag)
typedef __attribute__((ext_vector_type(4))) float floatx4;  // MFMA C/D frag

__device__ __forceinline__ ushort f2bf(float f) {           // RNE f32->bf16 bits
    uint u = __float_as_uint(f);
    uint r = u + 0x7FFFu + ((u >> 16) & 1u);
    return (ushort)(r >> 16);
}
__device__ __forceinline__ float bfu2f(ushort h) {
    return __uint_as_float(((uint)h) << 16);
}
__device__ __forceinline__ float bflo(uint u) { return __uint_as_float(u << 16); }
__device__ __forceinline__ float bfhi(uint u) { return __uint_as_float(u & 0xffff0000u); }
__device__ __forceinline__ float lrelu(float e) { return e >= 0.f ? e : 0.2f * e; }

// ---------------- CSR build (dst-sorted incoming edge lists) ----------------
__global__ void deg_kernel(const int* __restrict__ dst, int* __restrict__ cnt, int E) {
    int i = blockIdx.x * blockDim.x + threadIdx.x;
    if (i < E) atomicAdd(&cnt[dst[i]], 1);
}

__global__ __launch_bounds__(256) void scan1_kernel(const int* __restrict__ cnt,
                                                    int* __restrict__ excl,
                                                    int* __restrict__ partial, int n) {
    __shared__ int sd[256];
    int tid = threadIdx.x;
    int i = blockIdx.x * 256 + tid;
    int v = (i < n) ? cnt[i] : 0;
    sd[tid] = v;
    __syncthreads();
    #pragma unroll
    for (int off = 1; off < 256; off <<= 1) {
        int t = (tid >= off) ? sd[tid - off] : 0;
        __syncthreads();
        sd[tid] += t;
        __syncthreads();
    }
    if (i < n) excl[i] = sd[tid] - v;
    if (tid == 255) partial[blockIdx.x] = sd[255];
}

__global__ __launch_bounds__(256) void scan2_kernel(int* __restrict__ partial, int nb) {
    __shared__ int sd[256];
    int tid = threadIdx.x;
    int v = (tid < nb) ? partial[tid] : 0;
    sd[tid] = v;
    __syncthreads();
    #pragma unroll
    for (int off = 1; off < 256; off <<= 1) {
        int t = (tid >= off) ? sd[tid - off] : 0;
        __syncthreads();
        sd[tid] += t;
        __syncthreads();
    }
    if (tid < nb) partial[tid] = sd[tid] - v;   // exclusive
}

__global__ __launch_bounds__(256) void scan3_kernel(const int* __restrict__ excl,
                                                    const int* __restrict__ partial,
                                                    int* __restrict__ row_ptr,
                                                    int* __restrict__ row_tmp, int n) {
    int i = blockIdx.x * 256 + threadIdx.x;
    if (i < n) {
        int v = excl[i] + partial[blockIdx.x];
        row_ptr[i] = v;
        row_tmp[i] = v;
    }
    if (i == 0) row_ptr[n] = N_EDGES;
}

__global__ void scatter_kernel(const int* __restrict__ src, const int* __restrict__ dst,
                               int* __restrict__ row_tmp, int* __restrict__ sorted_src,
                               int* __restrict__ sorted_dst, int E) {
    int i = blockIdx.x * blockDim.x + threadIdx.x;
    if (i < E) {
        int d = dst[i];
        int p = atomicAdd(&row_tmp[d], 1);
        sorted_src[p] = src[i];
        sorted_dst[p] = d;
    }
}

// ---------------- W prep: transpose + bf16 hi/lo split, both layers ---------
__global__ void prep_w(const float* __restrict__ W1, const float* __restrict__ W2,
                       ushort* __restrict__ Wt1_hi, ushort* __restrict__ Wt1_lo,
                       ushort* __restrict__ Wt2_hi, ushort* __restrict__ Wt2_lo) {
    int n = threadIdx.x, k = blockIdx.x & 255;
    const float* W = (blockIdx.x < 256) ? W1 : W2;
    ushort* Wh = (blockIdx.x < 256) ? Wt1_hi : Wt2_hi;
    ushort* Wl = (blockIdx.x < 256) ? Wt1_lo : Wt2_lo;
    float v = W[k * 256 + n];
    ushort hb = f2bf(v);
    Wh[n * 256 + k] = hb;
    Wl[n * 256 + k] = f2bf(v - bfu2f(hb));
}

// ------- GEMM + fused attention logits, col-split -------
// Block: 64 rows x 128 cols; blockIdx.y=0 -> cols 0..127 (heads 0,1),
// blockIdx.y=1 -> cols 128..255 (heads 2,3). bf16x3 split MFMA.
__global__ __launch_bounds__(256) void gemm_att_kernel(const float* __restrict__ A,
                                                       const ushort* __restrict__ Wt_hi,
                                                       const ushort* __restrict__ Wt_lo,
                                                       const float* __restrict__ att_s,
                                                       const float* __restrict__ att_d,
                                                       ushort* __restrict__ H,
                                                       float* __restrict__ a_src,
                                                       float* __restrict__ a_dst, int M) {
    const int ROWP = 40;
    __shared__ ushort hi_s[128 * ROWP];   // 10 KB
    __shared__ ushort lo_s[128 * ROWP];   // 10 KB
    const int tid = threadIdx.x;
    const int wave = tid >> 6, lane = tid & 63;
    const int quad = lane >> 4, l16 = lane & 15;
    const int brow = blockIdx.x * 64;
    const int coff = blockIdx.y * 128;    // column offset (also Wt row offset)
    const int mrow = brow + wave * 16 + l16;
    const int mload = (mrow < M) ? mrow : (M - 1);

    floatx4 acc[8];
    #pragma unroll
    for (int t = 0; t < 8; t++) acc[t] = (floatx4){0.f, 0.f, 0.f, 0.f};

    for (int k0 = 0; k0 < 256; k0 += 32) {
        __syncthreads();
        {   // stage 128 cols x 32 k: threads 0-127 stage hi, 128-255 stage lo
            int t = tid & 127;
            const ushort* g = ((tid < 128) ? Wt_hi : Wt_lo) + (size_t)(coff + t) * 256 + k0;
            ushort* d = ((tid < 128) ? hi_s : lo_s) + t * ROWP;
            #pragma unroll
            for (int i = 0; i < 4; i++)
                *reinterpret_cast<short8*>(d + i * 8) =
                    *reinterpret_cast<const short8*>(g + i * 8);
        }
        __syncthreads();
        const float* ap = A + (size_t)mload * 256 + k0 + quad * 8;
        float4 a0 = *reinterpret_cast<const float4*>(ap);
        float4 a1 = *reinterpret_cast<const float4*>(ap + 4);
        float av[8] = {a0.x, a0.y, a0.z, a0.w, a1.x, a1.y, a1.z, a1.w};
        short8 a_hi, a_lo;
        #pragma unroll
        for (int j = 0; j < 8; j++) {
            ushort hb = f2bf(av[j]);
            a_hi[j] = (short)hb;
            a_lo[j] = (short)f2bf(av[j] - bfu2f(hb));
        }
        #pragma unroll
        for (int t = 0; t < 8; t++) {
            int roff = (t * 16 + l16) * ROWP + quad * 8;
            short8 b_hi = *reinterpret_cast<const short8*>(&hi_s[roff]);
            short8 b_lo = *reinterpret_cast<const short8*>(&lo_s[roff]);
            acc[t] = __builtin_amdgcn_mfma_f32_16x16x32_bf16(a_hi, b_hi, acc[t], 0, 0, 0);
            acc[t] = __builtin_amdgcn_mfma_f32_16x16x32_bf16(a_hi, b_lo, acc[t], 0, 0, 0);
            acc[t] = __builtin_amdgcn_mfma_f32_16x16x32_bf16(a_lo, b_hi, acc[t], 0, 0, 0);
        }
    }
    // fused attention-logit partials: tiles 0-3 -> head 2*by, 4-7 -> 2*by+1
    const int hb = blockIdx.y * 2;
    float ps[2][4] = {}, pd[2][4] = {};
    #pragma unroll
    for (int t = 0; t < 8; t++) {
        int hh = t >> 2;
        float as_v = att_s[coff + t * 16 + l16];
        float ad_v = att_d[coff + t * 16 + l16];
        #pragma unroll
        for (int r = 0; r < 4; r++) {
            ps[hh][r] += acc[t][r] * as_v;
            pd[hh][r] += acc[t][r] * ad_v;
        }
    }
    #pragma unroll
    for (int off = 1; off < 16; off <<= 1) {
        #pragma unroll
        for (int hh = 0; hh < 2; hh++)
            #pragma unroll
            for (int r = 0; r < 4; r++) {
                ps[hh][r] += __shfl_xor(ps[hh][r], off, 64);
                pd[hh][r] += __shfl_xor(pd[hh][r], off, 64);
            }
    }
    if (l16 == 0) {
        #pragma unroll
        for (int r = 0; r < 4; r++) {
            int m = brow + wave * 16 + quad * 4 + r;
            if (m < M) {
                #pragma unroll
                for (int hh = 0; hh < 2; hh++) {
                    a_src[m * 4 + hb + hh] = ps[hh][r];
                    a_dst[m * 4 + hb + hh] = pd[hh][r];
                }
            }
        }
    }
    // store bf16 H, plain layout
    #pragma unroll
    for (int t = 0; t < 8; t++) {
        int col = coff + t * 16 + l16;
        #pragma unroll
        for (int r = 0; r < 4; r++) {
            int m = brow + wave * 16 + quad * 4 + r;
            if (m < M) H[(size_t)m * 256 + col] = f2bf(acc[t][r]);
        }
    }
}

// ---------------- edge weights: w = exp(lrelu(a_src[s]+a_dst[d])) -----------
// No max-subtraction: logits bounded (|e| ~ O(10)), f32 exp safe; alpha = w/sum(w)
// is mathematically identical to the max-subtracted form.
__global__ __launch_bounds__(256) void ew_kernel(const float* __restrict__ a_src,
                                                 const float* __restrict__ a_dst,
                                                 const int* __restrict__ sorted_src,
                                                 const int* __restrict__ sorted_dst,
                                                 float* __restrict__ ew, int E) {
    int j = blockIdx.x * 256 + threadIdx.x;
    if (j >= E) return;
    int s = sorted_src[j], d = sorted_dst[j];
    float4 as_ = *reinterpret_cast<const float4*>(a_src + (size_t)s * 4);
    float4 ad_ = *reinterpret_cast<const float4*>(a_dst + (size_t)d * 4);
    float4 w;
    w.x = __expf(lrelu(as_.x + ad_.x));
    w.y = __expf(lrelu(as_.y + ad_.y));
    w.z = __expf(lrelu(as_.z + ad_.z));
    w.w = __expf(lrelu(as_.w + ad_.w));
    *reinterpret_cast<float4*>(ew + (size_t)j * 4) = w;
}

// ---------------- weighted gather, one wave per node, grid-stride -----------
// Two 32-lane halves process alternating edges. Within a half, lane hl covers
// 8 consecutive channels of ONE head (head=hl>>3, c0=8*(hl&7)) via one uint4
// load, weighted by a single scalar ew[4j+head].
__global__ __launch_bounds__(256) void agg_kernel(const ushort* __restrict__ H,
                                                  const float* __restrict__ a_src,
                                                  const float* __restrict__ a_dst,
                                                  const int* __restrict__ row_ptr,
                                                  const int* __restrict__ sorted_src,
                                                  const float* __restrict__ ew,
                                                  const float* __restrict__ bias,
                                                  float* __restrict__ out, int N) {
    const int wave = threadIdx.x >> 6, lane = threadIdx.x & 63;
    const int half = lane >> 5, hl = lane & 31;
    const int head = hl >> 3;
    const int hoff = head * 64 + (hl & 7) * 8;   // ushort offset within row

    for (int i = blockIdx.x * 4 + wave; i < N; i += gridDim.x * 4) {
        float wself = __expf(lrelu(a_src[i * 4 + head] + a_dst[i * 4 + head]));
        int start = row_ptr[i], end = row_ptr[i + 1];
        float c0 = 0.f, c1 = 0.f, c2 = 0.f, c3 = 0.f;
        float c4 = 0.f, c5 = 0.f, c6 = 0.f, c7 = 0.f;
        float dp = 0.f;
        int j = start + half;
        // unroll x2: two independent gather chains in flight
        for (; j + 2 < end; j += 4) {
            int s0 = sorted_src[j], s1 = sorted_src[j + 2];
            float w0 = ew[(size_t)j * 4 + head];
            float w1 = ew[(size_t)(j + 2) * 4 + head];
            uint4 h0 = *reinterpret_cast<const uint4*>(H + (size_t)s0 * 256 + hoff);
            uint4 h1 = *reinterpret_cast<const uint4*>(H + (size_t)s1 * 256 + hoff);
            c0 += w0 * bflo(h0.x); c1 += w0 * bfhi(h0.x);
            c2 += w0 * bflo(h0.y); c3 += w0 * bfhi(h0.y);
            c4 += w0 * bflo(h0.z); c5 += w0 * bfhi(h0.z);
            c6 += w0 * bflo(h0.w); c7 += w0 * bfhi(h0.w);
            dp += w0;
            c0 += w1 * bflo(h1.x); c1 += w1 * bfhi(h1.x);
            c2 += w1 * bflo(h1.y); c3 += w1 * bfhi(h1.y);
            c4 += w1 * bflo(h1.z); c5 += w1 * bfhi(h1.z);
            c6 += w1 * bflo(h1.w); c7 += w1 * bfhi(h1.w);
            dp += w1;
        }
        for (; j < end; j += 2) {
            int s0 = sorted_src[j];
            float w0 = ew[(size_t)j * 4 + head];
            uint4 h0 = *reinterpret_cast<const uint4*>(H + (size_t)s0 * 256 + hoff);
            c0 += w0 * bflo(h0.x); c1 += w0 * bfhi(h0.x);
            c2 += w0 * bflo(h0.y); c3 += w0 * bfhi(h0.y);
            c4 += w0 * bflo(h0.z); c5 += w0 * bfhi(h0.z);
            c6 += w0 * bflo(h0.w); c7 += w0 * bfhi(h0.w);
            dp += w0;
        }
        // merge halves (disjoint edges, same channels)
        c0 += __shfl_xor(c0, 32, 64); c1 += __shfl_xor(c1, 32, 64);
        c2 += __shfl_xor(c2, 32, 64); c3 += __shfl_xor(c3, 32, 64);
        c4 += __shfl_xor(c4, 32, 64); c5 += __shfl_xor(c5, 32, 64);
        c6 += __shfl_xor(c6, 32, 64); c7 += __shfl_xor(c7, 32, 64);
        dp += __shfl_xor(dp, 32, 64);
        if (half == 0) {
            // self loop
            uint4 hv = *reinterpret_cast<const uint4*>(H + (size_t)i * 256 + hoff);
            c0 += wself * bflo(hv.x); c1 += wself * bfhi(hv.x);
            c2 += wself * bflo(hv.y); c3 += wself * bfhi(hv.y);
            c4 += wself * bflo(hv.z); c5 += wself * bfhi(hv.z);
            c6 += wself * bflo(hv.w); c7 += wself * bfhi(hv.w);
            float r = 1.f / (dp + wself + 1e-16f);
            const float* bp = bias + hoff;
            float4 o;
            float v;
            v = c0 * r + bp[0]; o.x = (v > 0.f) ? v : expm1f(v);
            v = c1 * r + bp[1]; o.y = (v > 0.f) ? v : expm1f(v);
            v = c2 * r + bp[2]; o.z = (v > 0.f) ? v : expm1f(v);
            v = c3 * r + bp[3]; o.w = (v > 0.f) ? v : expm1f(v);
            *reinterpret_cast<float4*>(out + (size_t)i * 256 + hoff) = o;
            v = c4 * r + bp[4]; o.x = (v > 0.f) ? v : expm1f(v);
            v = c5 * r + bp[5]; o.y = (v > 0.f) ? v : expm1f(v);
            v = c6 * r + bp[6]; o.z = (v > 0.f) ? v : expm1f(v);
            v = c7 * r + bp[7]; o.w = (v > 0.f) ? v : expm1f(v);
            *reinterpret_cast<float4*>(out + (size_t)i * 256 + hoff + 4) = o;
        }
    }
}

extern "C" void kernel_launch(void* const* d_in, const int* in_sizes, int n_in,
                              void* d_out, int out_size, void* d_ws, size_t ws_size,
                              hipStream_t stream) {
    const float* x      = (const float*)d_in[0];
    const int*   eidx   = (const int*)d_in[1];
    const float* W1     = (const float*)d_in[2];
    const float* att_s1 = (const float*)d_in[3];
    const float* att_d1 = (const float*)d_in[4];
    const float* b1     = (const float*)d_in[5];
    const float* W2     = (const float*)d_in[6];
    const float* att_s2 = (const float*)d_in[7];
    const float* att_d2 = (const float*)d_in[8];
    const float* b2     = (const float*)d_in[9];
    float* out = (float*)d_out;

    const int N = N_NODES, E = N_EDGES;
    char* ws = (char*)d_ws;
    size_t off = 0;
    auto alloc = [&](size_t bytes) -> void* {
        void* p = ws + off;
        off += (bytes + 255) & ~(size_t)255;
        return p;
    };
    // total ws ~ 48 MB (proven-good envelope: 57 MB)
    ushort* h       = (ushort*)alloc((size_t)N * 256 * sizeof(ushort));  // 25.6 MB
    float*  ew      = (float*) alloc((size_t)E * 4 * sizeof(float));     // 12.8 MB
    float*  a_src   = (float*) alloc((size_t)N * 4 * sizeof(float));
    float*  a_dst   = (float*) alloc((size_t)N * 4 * sizeof(float));
    int*    cnt     = (int*)   alloc((size_t)N * sizeof(int));
    int*    row_ptr = (int*)   alloc((size_t)(N + 1) * sizeof(int));
    int*    row_tmp = (int*)   alloc((size_t)N * sizeof(int));
    int*    sorted  = (int*)   alloc((size_t)E * sizeof(int));
    int*    sortedd = (int*)   alloc((size_t)E * sizeof(int));
    int*    excl    = (int*)   alloc((size_t)N * sizeof(int));
    int*    partial = (int*)   alloc(256 * sizeof(int));
    ushort* Wt1_hi  = (ushort*)alloc(256 * 256 * sizeof(ushort));
    ushort* Wt1_lo  = (ushort*)alloc(256 * 256 * sizeof(ushort));
    ushort* Wt2_hi  = (ushort*)alloc(256 * 256 * sizeof(ushort));
    ushort* Wt2_lo  = (ushort*)alloc(256 * 256 * sizeof(ushort));
    float*  x2      = out;   // layer-1 f32 activations live in d_out, overwritten by layer 2
    (void)ws_size; (void)in_sizes; (void)n_in; (void)out_size;

    const int* e_src = eidx;
    const int* e_dst = eidx + E;
    const int nsb = (N + 255) / 256;   // 196 scan blocks
    const int neb = (E + 255) / 256;

    prep_w<<<512, 256, 0, stream>>>(W1, W2, Wt1_hi, Wt1_lo, Wt2_hi, Wt2_lo);
    hipMemsetAsync(cnt, 0, N * sizeof(int), stream);
    deg_kernel<<<neb, 256, 0, stream>>>(e_dst, cnt, E);
    scan1_kernel<<<nsb, 256, 0, stream>>>(cnt, excl, partial, N);
    scan2_kernel<<<1, 256, 0, stream>>>(partial, nsb);
    scan3_kernel<<<nsb, 256, 0, stream>>>(excl, partial, row_ptr, row_tmp, N);
    scatter_kernel<<<neb, 256, 0, stream>>>(e_src, e_dst, row_tmp, sorted, sortedd, E);

    dim3 ggrid((N + 63) / 64, 2);  // 782 x 2
    const int ablk = 2048;         // grid-stride agg: 8 blocks/CU
    // layer 1
    gemm_att_kernel<<<ggrid, 256, 0, stream>>>(x, Wt1_hi, Wt1_lo, att_s1, att_d1,
                                               h, a_src, a_dst, N);
    ew_kernel<<<neb, 256, 0, stream>>>(a_src, a_dst, sorted, sortedd, ew, E);
    agg_kernel<<<ablk, 256, 0, stream>>>(h, a_src, a_dst, row_ptr, sorted, ew, b1, x2, N);
    // layer 2
    gemm_att_kernel<<<ggrid, 256, 0, stream>>>(x2, Wt2_hi, Wt2_lo, att_s2, att_d2,
                                               h, a_src, a_dst, N);
    ew_kernel<<<neb, 256, 0, stream>>>(a_src, a_dst, sorted, sortedd, ew, E);
    agg_kernel<<<ablk, 256, 0, stream>>>(h, a_src, a_dst, row_ptr, sorted, ew, b2, out, N);
}